// Round 1
// baseline (402.761 us; speedup 1.0000x reference)
//
#include <hip/hip_runtime.h>
#include <cstdint>
#include <cstddef>

// ---- problem sizes ----
#define NPTS 32768      // B*H*W = 32*32*32
#define NE   1024       // codes
#define ED   256        // embedding dim (= C)
#define ZPLANE 262144   // 256*1024 floats per batch image (C*H*W)

// ---- output layout (floats) ----
#define OFF_LOSS 0
#define OFF_ZQ   1
#define OFF_PPL  8388609
#define OFF_ENC  8388610
#define OFF_IDX  41943042

// ---- ws layout (bytes) ----
#define WS_IDX   0          // int[32768]
#define WS_ZZ    131072     // float[32768]
#define WS_EE    262144     // float[1024]
#define WS_ET    266240     // float[256*1024] transposed codebook
#define WS_LOSSP 1314816    // double[8192]
#define NLOSSP   8192

// ======================================================================
// k_prep: per-code ||e||^2 with numpy pairwise order + transpose codebook
// ======================================================================
__global__ __launch_bounds__(256) void k_prep(const float* __restrict__ cb,
                                              float* __restrict__ ee,
                                              float* __restrict__ eT) {
#pragma clang fp contract(off)
    int k = blockIdx.x * 256 + threadIdx.x;
    if (k >= NE) return;
    const float* row = cb + (size_t)k * ED;
    float s[2];
    for (int h = 0; h < 2; ++h) {
        const float* a = row + h * 128;
        float r[8];
        for (int j = 0; j < 8; ++j) { float v = a[j]; r[j] = v * v; }
        for (int i = 8; i < 128; i += 8)
            for (int j = 0; j < 8; ++j) { float v = a[i + j]; r[j] += v * v; }
        s[h] = ((r[0] + r[1]) + (r[2] + r[3])) + ((r[4] + r[5]) + (r[6] + r[7]));
    }
    ee[k] = s[0] + s[1];
    for (int c = 0; c < ED; ++c) eT[(size_t)c * NE + k] = row[c];
}

// ======================================================================
// k_zz: per-point ||z||^2, numpy pairwise order. Coalesced: lane = w.
// ======================================================================
__global__ __launch_bounds__(256) void k_zz(const float* __restrict__ z,
                                            float* __restrict__ zz) {
#pragma clang fp contract(off)
    int n = blockIdx.x * 256 + threadIdx.x;      // 128 blocks
    int b = n >> 10, hw = n & 1023;
    const float* a0 = z + (size_t)b * ZPLANE + hw;
    float s[2];
    for (int h = 0; h < 2; ++h) {
        const float* a = a0 + (size_t)h * 128 * 1024;
        float r[8];
        for (int j = 0; j < 8; ++j) { float v = a[(size_t)j * 1024]; r[j] = v * v; }
        for (int i = 8; i < 128; i += 8)
            for (int j = 0; j < 8; ++j) { float v = a[(size_t)(i + j) * 1024]; r[j] += v * v; }
        s[h] = ((r[0] + r[1]) + (r[2] + r[3])) + ((r[4] + r[5]) + (r[6] + r[7]));
    }
    zz[n] = s[0] + s[1];
}

// ======================================================================
// k_main: distances + argmin.  Tile: 64 points x 128 codes, chunk c by 64.
// 256 threads: tcol=t&15 owns 8 codes, trow=t>>4 owns 4 points.
// ======================================================================
#define TM 64
#define TK 128
#define CCH 64

__global__ __launch_bounds__(256) void k_main(const float* __restrict__ z,
                                              const float* __restrict__ eT,
                                              const float* __restrict__ ee,
                                              const float* __restrict__ zz,
                                              int* __restrict__ idx_out) {
    __shared__ float zt[CCH][TM];      // 16 KB
    __shared__ float et[CCH][TK];      // 32 KB
    __shared__ float redv[TM][16];     // 4 KB
    __shared__ int   redi[TM][16];     // 4 KB
    __shared__ float bestv[TM];
    __shared__ int   besti[TM];
    __shared__ float zzl[TM];

    int t = threadIdx.x;
    int n0 = blockIdx.x * TM;                  // 512 blocks
    int b = n0 >> 10, hw0 = n0 & 1023;
    const float* zb = z + (size_t)b * ZPLANE + hw0;
    int trow = t >> 4, tcol = t & 15;

    if (t < TM) {
        bestv[t] = 3.4e38f; besti[t] = 0;
        zzl[t] = zz[n0 + t];
    }

    for (int kt = 0; kt < NE / TK; ++kt) {
        int k0 = kt * TK;
        float acc[4][8];
        for (int i = 0; i < 4; ++i)
            for (int j = 0; j < 8; ++j) acc[i][j] = 0.f;

        for (int cc = 0; cc < ED / CCH; ++cc) {
            __syncthreads();
            // load z tile (transposed): zt[c][m]
            {
                int m4 = (t & 15) * 4;
                int cb0 = t >> 4;
                for (int p = 0; p < 4; ++p) {
                    int cl = p * 16 + cb0;
                    float4 v = *(const float4*)(zb + (size_t)(cc * CCH + cl) * 1024 + m4);
                    *(float4*)&zt[cl][m4] = v;
                }
            }
            // load e tile (already transposed in eT): et[c][k]
            {
                int k4 = (t & 31) * 4;
                int cb0 = t >> 5;
                for (int p = 0; p < 8; ++p) {
                    int cl = p * 8 + cb0;
                    float4 v = *(const float4*)(eT + (size_t)(cc * CCH + cl) * 1024 + k0 + k4);
                    *(float4*)&et[cl][k4] = v;
                }
            }
            __syncthreads();
            for (int c = 0; c < CCH; ++c) {
                float4 zm = *(const float4*)&zt[c][trow * 4];
                float4 e0 = *(const float4*)&et[c][tcol * 8];
                float4 e1 = *(const float4*)&et[c][tcol * 8 + 4];
                float zv[4] = {zm.x, zm.y, zm.z, zm.w};
                float ev[8] = {e0.x, e0.y, e0.z, e0.w, e1.x, e1.y, e1.z, e1.w};
                for (int i = 0; i < 4; ++i)
                    for (int j = 0; j < 8; ++j)
                        acc[i][j] = fmaf(zv[i], ev[j], acc[i][j]);
            }
        }
        // per-thread local argmin (ascending k, strict < keeps lowest index)
        for (int i = 0; i < 4; ++i) {
            int m = trow * 4 + i;
            float zv = zzl[m];
            float bv = 3.4e38f; int bi = 0;
            for (int j = 0; j < 8; ++j) {
                int k = k0 + tcol * 8 + j;
                float t1 = zv + ee[k];          // fp32, matches ref broadcast add
                float d  = t1 - 2.0f * acc[i][j]; // 2*acc exact; one rounding
                if (d < bv) { bv = d; bi = k; }
            }
            redv[m][tcol] = bv; redi[m][tcol] = bi;
        }
        __syncthreads();
        if (t < TM) {
            float bv = bestv[t]; int bi = besti[t];
            for (int tc = 0; tc < 16; ++tc) {   // ascending k order
                float v = redv[t][tc]; int ix = redi[t][tc];
                if (v < bv || (v == bv && ix < bi)) { bv = v; bi = ix; }
            }
            bestv[t] = bv; besti[t] = bi;
        }
    }
    __syncthreads();
    if (t < TM) idx_out[n0 + t] = besti[t];
}

// ======================================================================
// k_out1: z_q straight-through output (B,C,H,W) + loss partial sums.
// Scalar coalesced (region base out+1 is not 16B-aligned).
// ======================================================================
__global__ __launch_bounds__(256) void k_out1(const float* __restrict__ z,
                                              const float* __restrict__ eT,
                                              const int* __restrict__ idx,
                                              float* __restrict__ out,
                                              double* __restrict__ lossp) {
#pragma clang fp contract(off)
    int t = threadIdx.x;
    double lsum = 0.0;
    for (int it = 0; it < 4; ++it) {
        int e = (blockIdx.x * 4 + it) * 256 + t;   // grid 8192 -> 8388608 elems
        int c  = (e >> 10) & 255;
        int bb = e >> 18;
        int hw = e & 1023;
        int n  = (bb << 10) + hw;
        int iv = idx[n];
        float zv = z[e];
        float zq = eT[(size_t)c * NE + iv];        // row c is L1-hot (4KB)
        float d  = zq - zv;                        // fp32
        out[OFF_ZQ + (size_t)e] = zv + d;          // straight-through semantics
        lsum += (double)(d * d);
    }
    // deterministic block reduction
    for (int off = 32; off; off >>= 1) lsum += __shfl_down(lsum, off);
    __shared__ double wsum[4];
    if ((t & 63) == 0) wsum[t >> 6] = lsum;
    __syncthreads();
    if (t == 0) lossp[blockIdx.x] = (wsum[0] + wsum[1]) + (wsum[2] + wsum[3]);
}

// ======================================================================
// k_out2: one-hot encodings (float2 stores; region base is 8B-aligned)
// + indices-as-float output.
// ======================================================================
__global__ __launch_bounds__(256) void k_out2(const int* __restrict__ idx,
                                              float* __restrict__ out) {
    int t = threadIdx.x;
    for (int it = 0; it < 16; ++it) {
        int q = (blockIdx.x * 16 + it) * 256 + t;  // grid 4096 -> 16777216 float2
        int row  = q >> 9;
        int col2 = (q & 511) * 2;
        int iv = idx[row];
        float2 v;
        v.x = (col2     == iv) ? 1.f : 0.f;
        v.y = (col2 + 1 == iv) ? 1.f : 0.f;
        *(float2*)(out + OFF_ENC + (size_t)q * 2) = v;
        if ((q & 511) == 0) out[OFF_IDX + row] = (float)iv;
    }
}

// ======================================================================
// k_final: perplexity (LDS histogram) + loss scalar. Deterministic.
// ======================================================================
__global__ __launch_bounds__(256) void k_final(const int* __restrict__ idx,
                                               const double* __restrict__ lossp,
                                               float* __restrict__ out) {
    __shared__ int cnt[NE];
    __shared__ double sh[4];
    int t = threadIdx.x;
    for (int k = t; k < NE; k += 256) cnt[k] = 0;
    __syncthreads();
    for (int n = t; n < NPTS; n += 256) atomicAdd(&cnt[idx[n]], 1);
    __syncthreads();

    // perplexity: e_mean exact in fp32 (count/2^15), fp32 log/mul like ref
    double psum = 0.0;
    for (int k = t; k < NE; k += 256) {
        float em = (float)cnt[k] / 32768.0f;
        float term = em * logf(em + 1e-10f);
        psum += (double)term;
    }
    for (int off = 32; off; off >>= 1) psum += __shfl_down(psum, off);
    if ((t & 63) == 0) sh[t >> 6] = psum;
    __syncthreads();
    if (t == 0) {
        double tot = (sh[0] + sh[1]) + (sh[2] + sh[3]);
        out[OFF_PPL] = expf(-(float)tot);
    }
    __syncthreads();

    // loss: fixed-order reduction of 8192 partials
    double ls = 0.0;
    for (int i = t; i < NLOSSP; i += 256) ls += lossp[i];
    for (int off = 32; off; off >>= 1) ls += __shfl_down(ls, off);
    __syncthreads();
    if ((t & 63) == 0) sh[t >> 6] = ls;
    __syncthreads();
    if (t == 0) {
        double m = ((sh[0] + sh[1]) + (sh[2] + sh[3])) / 8388608.0;
        float mf = (float)m;
        out[OFF_LOSS] = mf + 0.25f * mf;   // m1 + BETA*m2, m1==m2 numerically
    }
}

// ======================================================================
extern "C" void kernel_launch(void* const* d_in, const int* in_sizes, int n_in,
                              void* d_out, int out_size, void* d_ws, size_t ws_size,
                              hipStream_t stream) {
    const float* z  = (const float*)d_in[0];
    const float* cb = (const float*)d_in[1];
    float* out = (float*)d_out;
    char* ws = (char*)d_ws;

    int*    idx   = (int*)(ws + WS_IDX);
    float*  zz    = (float*)(ws + WS_ZZ);
    float*  ee    = (float*)(ws + WS_EE);
    float*  eT    = (float*)(ws + WS_ET);
    double* lossp = (double*)(ws + WS_LOSSP);

    k_prep <<<4,    256, 0, stream>>>(cb, ee, eT);
    k_zz   <<<128,  256, 0, stream>>>(z, zz);
    k_main <<<512,  256, 0, stream>>>(z, eT, ee, zz, idx);
    k_out1 <<<8192, 256, 0, stream>>>(z, eT, idx, out, lossp);
    k_out2 <<<4096, 256, 0, stream>>>(idx, out);
    k_final<<<1,    256, 0, stream>>>(idx, lossp, out);
}

// Round 2
// 367.444 us; speedup vs baseline: 1.0961x; 1.0961x over previous
//
#include <hip/hip_runtime.h>
#include <hip/hip_bf16.h>
#include <cstdint>
#include <cstddef>

typedef unsigned short u16;
typedef __attribute__((ext_vector_type(8))) short bf16x8;
typedef __attribute__((ext_vector_type(4))) float f32x4;

// ---- problem sizes ----
#define NPTS 32768      // B*H*W = 32*32*32
#define NE   1024       // codes
#define ED   256        // embedding dim (= C)
#define ZPLANE 262144   // 256*1024 floats per batch image (C*H*W)

// ---- output layout (floats) ----
#define OFF_LOSS 0
#define OFF_ZQ   1
#define OFF_PPL  8388609
#define OFF_ENC  8388610
#define OFF_IDX  41943042

// ---- ws layout (bytes) ----
#define WS_IDX   0              // int[32768]
#define WS_ZZ    131072         // float[32768]
#define WS_EE    262144         // float[1024]
#define WS_ET    266240         // float[256*1024]
#define WS_LOSSP 1314816        // double[8192]
#define NLOSSP   8192
#define WS_EH    1380352        // u16[1024*256]
#define WS_EL    1904640
#define WS_ZH    2428928        // u16[32768*256]
#define WS_ZL    19206144
#define WS_CCNT  35983360       // int[32768]
#define WS_CANDK 36114432       // int[32768*16]
#define WS_NEED  38211584ULL

#define MARGIN 3.0e-4f

// ======================================================================
// k_prep: ||e||^2 (numpy pairwise order), eT transpose, bf16 hi/lo split
// ======================================================================
__global__ __launch_bounds__(256) void k_prep(const float* __restrict__ cb,
                                              float* __restrict__ ee,
                                              float* __restrict__ eT,
                                              u16* __restrict__ eh,
                                              u16* __restrict__ el) {
#pragma clang fp contract(off)
    int k = blockIdx.x * 256 + threadIdx.x;
    if (k >= NE) return;
    const float* row = cb + (size_t)k * ED;
    float s[2];
    for (int h = 0; h < 2; ++h) {
        const float* a = row + h * 128;
        float r[8];
        for (int j = 0; j < 8; ++j) { float v = a[j]; r[j] = v * v; }
        for (int i = 8; i < 128; i += 8)
            for (int j = 0; j < 8; ++j) { float v = a[i + j]; r[j] += v * v; }
        s[h] = ((r[0] + r[1]) + (r[2] + r[3])) + ((r[4] + r[5]) + (r[6] + r[7]));
    }
    ee[k] = s[0] + s[1];
    for (int c = 0; c < ED; ++c) {
        float f = row[c];
        eT[(size_t)c * NE + k] = f;
        __hip_bfloat16 h = __float2bfloat16(f);
        float hf = __bfloat162float(h);
        __hip_bfloat16 l = __float2bfloat16(f - hf);
        eh[(size_t)k * ED + c] = *(u16*)&h;
        el[(size_t)k * ED + c] = *(u16*)&l;
    }
}

// k_prep_old: original (small-ws fallback)
__global__ __launch_bounds__(256) void k_prep_old(const float* __restrict__ cb,
                                                  float* __restrict__ ee,
                                                  float* __restrict__ eT) {
#pragma clang fp contract(off)
    int k = blockIdx.x * 256 + threadIdx.x;
    if (k >= NE) return;
    const float* row = cb + (size_t)k * ED;
    float s[2];
    for (int h = 0; h < 2; ++h) {
        const float* a = row + h * 128;
        float r[8];
        for (int j = 0; j < 8; ++j) { float v = a[j]; r[j] = v * v; }
        for (int i = 8; i < 128; i += 8)
            for (int j = 0; j < 8; ++j) { float v = a[i + j]; r[j] += v * v; }
        s[h] = ((r[0] + r[1]) + (r[2] + r[3])) + ((r[4] + r[5]) + (r[6] + r[7]));
    }
    ee[k] = s[0] + s[1];
    for (int c = 0; c < ED; ++c) eT[(size_t)c * NE + k] = row[c];
}

// ======================================================================
// k_zz: per-point ||z||^2, numpy pairwise order (proven exact)
// ======================================================================
__global__ __launch_bounds__(256) void k_zz(const float* __restrict__ z,
                                            float* __restrict__ zz) {
#pragma clang fp contract(off)
    int n = blockIdx.x * 256 + threadIdx.x;      // 128 blocks
    int b = n >> 10, hw = n & 1023;
    const float* a0 = z + (size_t)b * ZPLANE + hw;
    float s[2];
    for (int h = 0; h < 2; ++h) {
        const float* a = a0 + (size_t)h * 128 * 1024;
        float r[8];
        for (int j = 0; j < 8; ++j) { float v = a[(size_t)j * 1024]; r[j] = v * v; }
        for (int i = 8; i < 128; i += 8)
            for (int j = 0; j < 8; ++j) { float v = a[(size_t)(i + j) * 1024]; r[j] += v * v; }
        s[h] = ((r[0] + r[1]) + (r[2] + r[3])) + ((r[4] + r[5]) + (r[6] + r[7]));
    }
    zz[n] = s[0] + s[1];
}

// ======================================================================
// k_zsplit: transpose z (b,c,hw)->point-major + bf16 hi/lo split
// ======================================================================
__global__ __launch_bounds__(256) void k_zsplit(const float* __restrict__ z,
                                                u16* __restrict__ zh,
                                                u16* __restrict__ zl) {
    __shared__ float tile[64][65];
    int t = threadIdx.x;
    int blk = blockIdx.x;              // 2048 = 32b * 4c * 16hw
    int b   = blk >> 6;
    int c0  = ((blk >> 4) & 3) * 64;
    int hw0 = (blk & 15) * 64;
    int lane = t & 63, q = t >> 6;
    for (int i = 0; i < 16; ++i) {
        int cl = i * 4 + q;
        tile[cl][lane] = z[(size_t)b * ZPLANE + (size_t)(c0 + cl) * 1024 + hw0 + lane];
    }
    __syncthreads();
    int p = t >> 2, cq = t & 3;
    size_t n = (size_t)b * 1024 + hw0 + p;
    u16 hbuf[16], lbuf[16];
#pragma unroll
    for (int k = 0; k < 16; ++k) {
        float f = tile[cq * 16 + k][p];
        __hip_bfloat16 h = __float2bfloat16(f);
        float hf = __bfloat162float(h);
        __hip_bfloat16 l = __float2bfloat16(f - hf);
        hbuf[k] = *(u16*)&h; lbuf[k] = *(u16*)&l;
    }
    u16* dh = zh + n * 256 + c0 + cq * 16;
    u16* dl = zl + n * 256 + c0 + cq * 16;
    *(bf16x8*)(dh)     = *(bf16x8*)&hbuf[0];
    *(bf16x8*)(dh + 8) = *(bf16x8*)&hbuf[8];
    *(bf16x8*)(dl)     = *(bf16x8*)&lbuf[0];
    *(bf16x8*)(dl + 8) = *(bf16x8*)&lbuf[8];
}

// ======================================================================
// k_filter: bf16x3 MFMA approximate scores + margin candidate emission.
// Block: 256 thr (4 waves), 128 points; N-chunks of 128 codes; K=256.
// Wave w owns points w*32 + (lane&15) and +16 (two 16-row fragments).
// ======================================================================
__global__ __launch_bounds__(256) void k_filter(const u16* __restrict__ zh,
                                                const u16* __restrict__ zl,
                                                const u16* __restrict__ eh,
                                                const u16* __restrict__ el,
                                                const float* __restrict__ ee,
                                                int* __restrict__ candcnt,
                                                int* __restrict__ candk) {
    __shared__ u16  Bh[128 * 64];     // 16 KB, XOR-swizzled
    __shared__ u16  Bl[128 * 64];     // 16 KB
    __shared__ float eeL[128];
    __shared__ int  cntL[128];
    __shared__ int  ckL[128][16];

    int t = threadIdx.x;
    int lane = t & 63, w = t >> 6;
    int n0 = blockIdx.x * 128;                    // 256 blocks
    int prow = w * 32 + (lane & 15);
    const u16* zh0 = zh + (size_t)(n0 + prow) * 256;
    const u16* zl0 = zl + (size_t)(n0 + prow) * 256;
    const u16* zh1 = zh0 + 16 * 256;
    const u16* zl1 = zl0 + 16 * 256;
    int koff_lane = (lane >> 4) * 8;

    if (t < 128) cntL[t] = 0;
    float runmin[2][4];
#pragma unroll
    for (int g = 0; g < 2; ++g)
#pragma unroll
        for (int j = 0; j < 4; ++j) runmin[g][j] = 3.4e38f;

    for (int nc = 0; nc < 8; ++nc) {
        f32x4 acc0[8], acc1[8];
#pragma unroll
        for (int nf = 0; nf < 8; ++nf) {
            acc0[nf] = (f32x4){0.f, 0.f, 0.f, 0.f};
            acc1[nf] = (f32x4){0.f, 0.f, 0.f, 0.f};
        }
        for (int kb = 0; kb < 4; ++kb) {
            __syncthreads();
            if (kb == 0 && t < 128) eeL[t] = ee[nc * 128 + t];
#pragma unroll
            for (int i = 0; i < 8; ++i) {
                int f = i * 256 + t;
                int a = f >> 10, r = (f >> 3) & 127, seg = f & 7;
                const u16* src = (a ? el : eh) + (size_t)(nc * 128 + r) * 256 + kb * 64 + seg * 8;
                bf16x8 v = *(const bf16x8*)src;
                int bo = (r * 128 + seg * 16) ^ ((r & 7) << 4);
                *(bf16x8*)((char*)(a ? Bl : Bh) + bo) = v;
            }
            __syncthreads();
#pragma unroll
            for (int ks2 = 0; ks2 < 2; ++ks2) {
                int ko = kb * 64 + ks2 * 32 + koff_lane;
                bf16x8 ah0 = *(const bf16x8*)(zh0 + ko);
                bf16x8 al0 = *(const bf16x8*)(zl0 + ko);
                bf16x8 ah1 = *(const bf16x8*)(zh1 + ko);
                bf16x8 al1 = *(const bf16x8*)(zl1 + ko);
#pragma unroll
                for (int nf = 0; nf < 8; ++nf) {
                    int r = nf * 16 + (lane & 15);
                    int bo = (r * 128 + ks2 * 64 + (lane >> 4) * 16) ^ ((r & 7) << 4);
                    bf16x8 bh = *(const bf16x8*)((const char*)Bh + bo);
                    bf16x8 bl = *(const bf16x8*)((const char*)Bl + bo);
                    acc0[nf] = __builtin_amdgcn_mfma_f32_16x16x32_bf16(ah0, bh, acc0[nf], 0, 0, 0);
                    acc0[nf] = __builtin_amdgcn_mfma_f32_16x16x32_bf16(al0, bh, acc0[nf], 0, 0, 0);
                    acc0[nf] = __builtin_amdgcn_mfma_f32_16x16x32_bf16(ah0, bl, acc0[nf], 0, 0, 0);
                    acc1[nf] = __builtin_amdgcn_mfma_f32_16x16x32_bf16(ah1, bh, acc1[nf], 0, 0, 0);
                    acc1[nf] = __builtin_amdgcn_mfma_f32_16x16x32_bf16(al1, bh, acc1[nf], 0, 0, 0);
                    acc1[nf] = __builtin_amdgcn_mfma_f32_16x16x32_bf16(ah1, bl, acc1[nf], 0, 0, 0);
                }
            }
        }
        // epilogue: s = ee - 2*dot'; chunk-min; emission vs running min
#pragma unroll
        for (int g = 0; g < 2; ++g) {
#pragma unroll
            for (int nf = 0; nf < 8; ++nf) {
                float eev = eeL[nf * 16 + (lane & 15)];
                f32x4 d = g ? acc1[nf] : acc0[nf];
                f32x4 s;
#pragma unroll
                for (int j = 0; j < 4; ++j) s[j] = fmaf(-2.f, d[j], eev);
                if (g) acc1[nf] = s; else acc0[nf] = s;
            }
#pragma unroll
            for (int j = 0; j < 4; ++j) {
                float m = 3.4e38f;
#pragma unroll
                for (int nf = 0; nf < 8; ++nf) m = fminf(m, g ? acc1[nf][j] : acc0[nf][j]);
                m = fminf(m, __shfl_xor(m, 1, 64));
                m = fminf(m, __shfl_xor(m, 2, 64));
                m = fminf(m, __shfl_xor(m, 4, 64));
                m = fminf(m, __shfl_xor(m, 8, 64));
                runmin[g][j] = fminf(runmin[g][j], m);
                float th = runmin[g][j] + MARGIN;
                int ml = w * 32 + g * 16 + (lane >> 4) * 4 + j;
#pragma unroll
                for (int nf = 0; nf < 8; ++nf) {
                    float sv = g ? acc1[nf][j] : acc0[nf][j];
                    if (sv <= th) {
                        int pos = atomicAdd(&cntL[ml], 1);
                        if (pos < 16) ckL[ml][pos] = nc * 128 + nf * 16 + (lane & 15);
                    }
                }
            }
        }
    }
    __syncthreads();
    if (t < 128) {
        int n = n0 + t;
        candcnt[n] = cntL[t];
#pragma unroll
        for (int p = 0; p < 4; ++p)
            *(int4*)(candk + (size_t)n * 16 + p * 4) = *(int4*)&ckL[t][p * 4];
    }
}

// ======================================================================
// k_rescore: exact fp32 d (ref arithmetic) over candidates; argmin with
// lowest-index tie-break. Full scan fallback if cnt>16.
// ======================================================================
__global__ __launch_bounds__(256) void k_rescore(const float* __restrict__ z,
                                                 const float* __restrict__ cb,
                                                 const float* __restrict__ ee,
                                                 const float* __restrict__ zz,
                                                 const int* __restrict__ candcnt,
                                                 const int* __restrict__ candk,
                                                 int* __restrict__ idx_out) {
    int t = threadIdx.x;
    int n = blockIdx.x * 256 + t;                 // 128 blocks
    int b = n >> 10, hw = n & 1023;
    const float* zp = z + (size_t)b * ZPLANE + hw;
    int cnt = candcnt[n];
    bool full = cnt > 16;
    int total = full ? NE : cnt;
    const int* cl = candk + (size_t)n * 16;
    float zzv = zz[n];
    float bd = 3.4e38f; int bk = 1 << 30;
    for (int p = 0; p < total; p += 4) {
        int r = total - p;
        int k0 = full ? p     : cl[p];
        int k1 = full ? p + 1 : cl[(r > 1) ? p + 1 : p];
        int k2 = full ? p + 2 : cl[(r > 2) ? p + 2 : p];
        int k3 = full ? p + 3 : cl[(r > 3) ? p + 3 : p];
        const float* e0 = cb + (size_t)k0 * ED;
        const float* e1 = cb + (size_t)k1 * ED;
        const float* e2 = cb + (size_t)k2 * ED;
        const float* e3 = cb + (size_t)k3 * ED;
        float a0 = 0.f, a1 = 0.f, a2 = 0.f, a3 = 0.f;
        for (int c = 0; c < ED; ++c) {
            float zc = zp[(size_t)c * 1024];
            a0 = fmaf(zc, e0[c], a0);
            a1 = fmaf(zc, e1[c], a1);
            a2 = fmaf(zc, e2[c], a2);
            a3 = fmaf(zc, e3[c], a3);
        }
        float d0 = (zzv + ee[k0]) - 2.f * a0;
        float d1 = (zzv + ee[k1]) - 2.f * a1;
        float d2 = (zzv + ee[k2]) - 2.f * a2;
        float d3 = (zzv + ee[k3]) - 2.f * a3;
        if (d0 < bd || (d0 == bd && k0 < bk)) { bd = d0; bk = k0; }
        if (d1 < bd || (d1 == bd && k1 < bk)) { bd = d1; bk = k1; }
        if (d2 < bd || (d2 == bd && k2 < bk)) { bd = d2; bk = k2; }
        if (d3 < bd || (d3 == bd && k3 < bk)) { bd = d3; bk = k3; }
    }
    idx_out[n] = bk;
}

// ======================================================================
// k_main (fallback path only): exact fp32 distances + argmin, proven.
// ======================================================================
#define TM 64
#define TK 128
#define CCH 64
__global__ __launch_bounds__(256) void k_main(const float* __restrict__ z,
                                              const float* __restrict__ eT,
                                              const float* __restrict__ ee,
                                              const float* __restrict__ zz,
                                              int* __restrict__ idx_out) {
    __shared__ float zt[CCH][TM];
    __shared__ float et[CCH][TK];
    __shared__ float redv[TM][16];
    __shared__ int   redi[TM][16];
    __shared__ float bestv[TM];
    __shared__ int   besti[TM];
    __shared__ float zzl[TM];
    int t = threadIdx.x;
    int n0 = blockIdx.x * TM;
    int b = n0 >> 10, hw0 = n0 & 1023;
    const float* zb = z + (size_t)b * ZPLANE + hw0;
    int trow = t >> 4, tcol = t & 15;
    if (t < TM) { bestv[t] = 3.4e38f; besti[t] = 0; zzl[t] = zz[n0 + t]; }
    for (int kt = 0; kt < NE / TK; ++kt) {
        int k0 = kt * TK;
        float acc[4][8];
        for (int i = 0; i < 4; ++i)
            for (int j = 0; j < 8; ++j) acc[i][j] = 0.f;
        for (int cc = 0; cc < ED / CCH; ++cc) {
            __syncthreads();
            {
                int m4 = (t & 15) * 4; int cb0 = t >> 4;
                for (int p = 0; p < 4; ++p) {
                    int cl = p * 16 + cb0;
                    float4 v = *(const float4*)(zb + (size_t)(cc * CCH + cl) * 1024 + m4);
                    *(float4*)&zt[cl][m4] = v;
                }
            }
            {
                int k4 = (t & 31) * 4; int cb0 = t >> 5;
                for (int p = 0; p < 8; ++p) {
                    int cl = p * 8 + cb0;
                    float4 v = *(const float4*)(eT + (size_t)(cc * CCH + cl) * 1024 + k0 + k4);
                    *(float4*)&et[cl][k4] = v;
                }
            }
            __syncthreads();
            for (int c = 0; c < CCH; ++c) {
                float4 zm = *(const float4*)&zt[c][trow * 4];
                float4 e0 = *(const float4*)&et[c][tcol * 8];
                float4 e1 = *(const float4*)&et[c][tcol * 8 + 4];
                float zv[4] = {zm.x, zm.y, zm.z, zm.w};
                float ev[8] = {e0.x, e0.y, e0.z, e0.w, e1.x, e1.y, e1.z, e1.w};
                for (int i = 0; i < 4; ++i)
                    for (int j = 0; j < 8; ++j)
                        acc[i][j] = fmaf(zv[i], ev[j], acc[i][j]);
            }
        }
        for (int i = 0; i < 4; ++i) {
            int m = trow * 4 + i;
            float zv = zzl[m];
            float bv = 3.4e38f; int bi = 0;
            for (int j = 0; j < 8; ++j) {
                int k = k0 + tcol * 8 + j;
                float t1 = zv + ee[k];
                float d  = t1 - 2.0f * acc[i][j];
                if (d < bv) { bv = d; bi = k; }
            }
            redv[m][tcol] = bv; redi[m][tcol] = bi;
        }
        __syncthreads();
        if (t < TM) {
            float bv = bestv[t]; int bi = besti[t];
            for (int tc = 0; tc < 16; ++tc) {
                float v = redv[t][tc]; int ix = redi[t][tc];
                if (v < bv || (v == bv && ix < bi)) { bv = v; bi = ix; }
            }
            bestv[t] = bv; besti[t] = bi;
        }
    }
    __syncthreads();
    if (t < TM) idx_out[n0 + t] = besti[t];
}

// ======================================================================
// k_out1: z_q straight-through (B,C,H,W) + loss partials
// ======================================================================
__global__ __launch_bounds__(256) void k_out1(const float* __restrict__ z,
                                              const float* __restrict__ eT,
                                              const int* __restrict__ idx,
                                              float* __restrict__ out,
                                              double* __restrict__ lossp) {
#pragma clang fp contract(off)
    int t = threadIdx.x;
    double lsum = 0.0;
    for (int it = 0; it < 4; ++it) {
        int e = (blockIdx.x * 4 + it) * 256 + t;
        int c  = (e >> 10) & 255;
        int bb = e >> 18;
        int hw = e & 1023;
        int n  = (bb << 10) + hw;
        int iv = idx[n];
        float zv = z[e];
        float zq = eT[(size_t)c * NE + iv];
        float d  = zq - zv;
        out[OFF_ZQ + (size_t)e] = zv + d;
        lsum += (double)(d * d);
    }
    for (int off = 32; off; off >>= 1) lsum += __shfl_down(lsum, off);
    __shared__ double wsum[4];
    if ((t & 63) == 0) wsum[t >> 6] = lsum;
    __syncthreads();
    if (t == 0) lossp[blockIdx.x] = (wsum[0] + wsum[1]) + (wsum[2] + wsum[3]);
}

// ======================================================================
// k_out2: one-hot encodings + indices
// ======================================================================
__global__ __launch_bounds__(256) void k_out2(const int* __restrict__ idx,
                                              float* __restrict__ out) {
    int t = threadIdx.x;
    for (int it = 0; it < 16; ++it) {
        int q = (blockIdx.x * 16 + it) * 256 + t;
        int row  = q >> 9;
        int col2 = (q & 511) * 2;
        int iv = idx[row];
        float2 v;
        v.x = (col2     == iv) ? 1.f : 0.f;
        v.y = (col2 + 1 == iv) ? 1.f : 0.f;
        *(float2*)(out + OFF_ENC + (size_t)q * 2) = v;
        if ((q & 511) == 0) out[OFF_IDX + row] = (float)iv;
    }
}

// ======================================================================
// k_final: perplexity + loss scalar, deterministic
// ======================================================================
__global__ __launch_bounds__(256) void k_final(const int* __restrict__ idx,
                                               const double* __restrict__ lossp,
                                               float* __restrict__ out) {
    __shared__ int cnt[NE];
    __shared__ double sh[4];
    int t = threadIdx.x;
    for (int k = t; k < NE; k += 256) cnt[k] = 0;
    __syncthreads();
    for (int n = t; n < NPTS; n += 256) atomicAdd(&cnt[idx[n]], 1);
    __syncthreads();
    double psum = 0.0;
    for (int k = t; k < NE; k += 256) {
        float em = (float)cnt[k] / 32768.0f;
        float term = em * logf(em + 1e-10f);
        psum += (double)term;
    }
    for (int off = 32; off; off >>= 1) psum += __shfl_down(psum, off);
    if ((t & 63) == 0) sh[t >> 6] = psum;
    __syncthreads();
    if (t == 0) {
        double tot = (sh[0] + sh[1]) + (sh[2] + sh[3]);
        out[OFF_PPL] = expf(-(float)tot);
    }
    __syncthreads();
    double ls = 0.0;
    for (int i = t; i < NLOSSP; i += 256) ls += lossp[i];
    for (int off = 32; off; off >>= 1) ls += __shfl_down(ls, off);
    __syncthreads();
    if ((t & 63) == 0) sh[t >> 6] = ls;
    __syncthreads();
    if (t == 0) {
        double m = ((sh[0] + sh[1]) + (sh[2] + sh[3])) / 8388608.0;
        float mf = (float)m;
        out[OFF_LOSS] = mf + 0.25f * mf;
    }
}

// ======================================================================
extern "C" void kernel_launch(void* const* d_in, const int* in_sizes, int n_in,
                              void* d_out, int out_size, void* d_ws, size_t ws_size,
                              hipStream_t stream) {
    const float* z  = (const float*)d_in[0];
    const float* cb = (const float*)d_in[1];
    float* out = (float*)d_out;
    char* ws = (char*)d_ws;

    int*    idx   = (int*)(ws + WS_IDX);
    float*  zz    = (float*)(ws + WS_ZZ);
    float*  ee    = (float*)(ws + WS_EE);
    float*  eT    = (float*)(ws + WS_ET);
    double* lossp = (double*)(ws + WS_LOSSP);

    if (ws_size >= WS_NEED) {
        u16* eh = (u16*)(ws + WS_EH);
        u16* el = (u16*)(ws + WS_EL);
        u16* zh = (u16*)(ws + WS_ZH);
        u16* zl = (u16*)(ws + WS_ZL);
        int* ccnt  = (int*)(ws + WS_CCNT);
        int* candk = (int*)(ws + WS_CANDK);

        k_prep   <<<4,    256, 0, stream>>>(cb, ee, eT, eh, el);
        k_zz     <<<128,  256, 0, stream>>>(z, zz);
        k_zsplit <<<2048, 256, 0, stream>>>(z, zh, zl);
        k_filter <<<256,  256, 0, stream>>>(zh, zl, eh, el, ee, ccnt, candk);
        k_rescore<<<128,  256, 0, stream>>>(z, cb, ee, zz, ccnt, candk, idx);
    } else {
        k_prep_old<<<4,   256, 0, stream>>>(cb, ee, eT);
        k_zz      <<<128, 256, 0, stream>>>(z, zz);
        k_main    <<<512, 256, 0, stream>>>(z, eT, ee, zz, idx);
    }
    k_out1 <<<8192, 256, 0, stream>>>(z, eT, idx, out, lossp);
    k_out2 <<<4096, 256, 0, stream>>>(idx, out);
    k_final<<<1,    256, 0, stream>>>(idx, lossp, out);
}